// Round 8
// baseline (811.135 us; speedup 1.0000x reference)
//
#include <hip/hip_runtime.h>

// FNO spectral convolution, truncated separable DFT formulation.
// B=8, H=W=256, C_IN=C_OUT=64, modes 32 x 17 (rows fftshift-centered: k_m = m-16).
//
// ROUND-8 DIAGNOSTIC BUILD: k1/k3 rewritten as Goertzel/Horner recurrences
// (zero in-loop twiddle traffic; constants in SGPRs / exact i^wq seeds) AND
// internally replicated x8 (each rep covers a shifted bijection of the real
// rows, writing identical values) so their dispatches exceed the ~75us
// harness-fill cutoff and appear in rocprof top-5 with honest counters.
// Next round drops NREP to 1 once counters identify the limiter.
//
// ws layout (floats):
//   twA [256 w][17 n][2]  : 8704      (k1 uses only row w=1 now; k0 kept as-is)
//   twB [256 h][32 m][2]  : 16384
//   G   [B][H][17][64][2] : 4456448   (aliased by Z after k2a)
//   T   [B][H][17][64][2] : 4456448   (aliased by P before k2c)
//   P [4 hq][136 bn][32 m][64 i][2] -> lives in T's slot
//   Z [8 b][17 n][32 m][64 o][2]    -> lives in dead G's slot

#define NB 8
#define NH 256
#define NW 256
#define NC 64
#define NM1 32
#define NM2 17
#define HQ 4
#define NREP 8

__global__ void k0_tw(float* __restrict__ twA, float* __restrict__ twB) {
    const float STEP = 0.02454369260617026f; // 2*pi/256
    int t = blockIdx.x * 256 + threadIdx.x;
    if (t < 256 * 17) {
        int w = t / 17, n = t % 17;
        int ph = (n * w) & 255;
        float ang = (float)ph * STEP;
        twA[t * 2 + 0] = cosf(ang);
        twA[t * 2 + 1] = sinf(ang);
    }
    if (t < 256 * 32) {
        int h = t >> 5, m = t & 31;
        int ph = ((m - 16) * h) & 255;
        float ang = (float)ph * STEP;
        twB[t * 2 + 0] = cosf(ang);
        twB[t * 2 + 1] = sinf(ang);
    }
}

// K1 (Goertzel): G[n][i] = sum_w x[bh,w,i] * cis(-2pi n w/256).
// Per wave: Horner over its 64-w quarter in q_n = cis(-2pi n/256) (17 SGPR-resident
// complex constants, s_loaded ONCE from twA row w=1), then exact (-i)^(n*wq)
// rotation, then 4-way LDS reduce. Inner loop: 2 coalesced loads + 136 FMA, no
// other memory. 2 rows/block, grid 1024 pairs; NREP reps over shifted pairs.
__global__ __launch_bounds__(256) void k1_fwdW(const float* __restrict__ x,
                                               const float* __restrict__ twA,
                                               float* __restrict__ G) {
    __shared__ float lre[4][17][64];
    __shared__ float lim[4][17][64];
    const int tid = threadIdx.x;
    const int i = tid & 63;
    const int wq_u = __builtin_amdgcn_readfirstlane(tid >> 6);

    // z_n = (c_n, -s_n); store (zr, zs) = (cos, sin), apply sign in the FMAs.
    const float* tw1 = twA + 34; // row w=1
    float zr[17], zs[17];
    #pragma unroll
    for (int n = 0; n < 17; ++n) { zr[n] = tw1[2 * n]; zs[n] = tw1[2 * n + 1]; }

    #pragma unroll 1
    for (int rep = 0; rep < NREP; ++rep) {
        const int pb = (blockIdx.x + rep * 131) & 1023;  // bijection per rep
        const int bh0 = pb * 2;

        float ar0[17], ai0[17], ar1[17], ai1[17];
        #pragma unroll
        for (int n = 0; n < 17; ++n) { ar0[n]=0.f; ai0[n]=0.f; ar1[n]=0.f; ai1[n]=0.f; }

        const float* xb0 = x + (size_t)bh0 * (NW * NC) + (size_t)wq_u * 64 * 64 + i;
        const float* xb1 = xb0 + NW * NC;
        // Horner consumes coefficients high->low: acc = acc*q + x_ww, ww=63..0
        #pragma unroll 2
        for (int ww = 63; ww >= 0; --ww) {
            float xv0 = xb0[(size_t)ww * 64];   // coalesced 256B/wave
            float xv1 = xb1[(size_t)ww * 64];
            #pragma unroll
            for (int n = 0; n < 17; ++n) {
                // acc*(zr,-zs)+x :  nr = ar*zr + ai*zs + x ;  ni = ai*zr - ar*zs
                float t0  = fmaf(ai0[n], zs[n], xv0);
                float u0  = ar0[n] * zs[n];
                float nr0 = fmaf(ar0[n], zr[n], t0);
                float ni0 = fmaf(ai0[n], zr[n], -u0);
                ar0[n] = nr0; ai0[n] = ni0;
                float t1  = fmaf(ai1[n], zs[n], xv1);
                float u1  = ar1[n] * zs[n];
                float nr1 = fmaf(ar1[n], zr[n], t1);
                float ni1 = fmaf(ai1[n], zr[n], -u1);
                ar1[n] = nr1; ai1[n] = ni1;
            }
        }

        // rotate partial by cis(-2pi*n*64*wq/256) = (-i)^(n*wq): exact selects
        #pragma unroll
        for (int n = 0; n < 17; ++n) {
            int k = (n * wq_u) & 3;
            float p0r = ar0[n], p0i = ai0[n], p1r = ar1[n], p1i = ai1[n];
            float r0r = (k==0)? p0r : (k==1)? p0i : (k==2)? -p0r : -p0i;
            float r0i = (k==0)? p0i : (k==1)? -p0r : (k==2)? -p0i : p0r;
            float r1r = (k==0)? p1r : (k==1)? p1i : (k==2)? -p1r : -p1i;
            float r1i = (k==0)? p1i : (k==1)? -p1r : (k==2)? -p1i : p1r;
            ar0[n] = r0r; ai0[n] = r0i; ar1[n] = r1r; ai1[n] = r1i;
        }

        // ---- reduce + store row 0 ----
        #pragma unroll
        for (int n = 0; n < 17; ++n) { lre[wq_u][n][i] = ar0[n]; lim[wq_u][n][i] = ai0[n]; }
        __syncthreads();
        float2* G0 = (float2*)G + (size_t)bh0 * 17 * 64;
        for (int n = wq_u; n < 17; n += 4) {
            float re = (lre[0][n][i] + lre[1][n][i]) + (lre[2][n][i] + lre[3][n][i]);
            float im = (lim[0][n][i] + lim[1][n][i]) + (lim[2][n][i] + lim[3][n][i]);
            G0[n * 64 + i] = make_float2(re, im);
        }
        __syncthreads();
        // ---- reduce + store row 1 ----
        #pragma unroll
        for (int n = 0; n < 17; ++n) { lre[wq_u][n][i] = ar1[n]; lim[wq_u][n][i] = ai1[n]; }
        __syncthreads();
        float2* G1 = G0 + 17 * 64;
        for (int n = wq_u; n < 17; n += 4) {
            float re = (lre[0][n][i] + lre[1][n][i]) + (lre[2][n][i] + lre[3][n][i]);
            float im = (lim[0][n][i] + lim[1][n][i]) + (lim[2][n][i] + lim[3][n][i]);
            G1[n * 64 + i] = make_float2(re, im);
        }
        __syncthreads();   // LDS reused next rep
    }
}

// K2a: partial H-DFT. grid (136 bn, 4 hq). (unchanged from round 7)
__global__ __launch_bounds__(256) void k2a_hdft(const float* __restrict__ G,
                                                const float* __restrict__ twB,
                                                float* __restrict__ P) {
    const int bn = blockIdx.x;
    const int b = bn / 17, n = bn % 17;
    const int hq = blockIdx.y;
    const int t = threadIdx.x;
    const int lane = t & 63;
    const int q_u = __builtin_amdgcn_readfirstlane(t >> 6);

    float ar[8], ai[8];
    #pragma unroll
    for (int j = 0; j < 8; ++j) { ar[j] = 0.f; ai[j] = 0.f; }

    const float2* Gb = (const float2*)G + ((size_t)b * 256 * 17 + n) * 64 + lane;
    #pragma unroll 2
    for (int hh = 0; hh < 64; ++hh) {
        int h = hq * 64 + hh;
        float2 g = Gb[(size_t)h * (17 * 64)];
        const float* tw = twB + (h * 32 + q_u * 8) * 2;
        #pragma unroll
        for (int j = 0; j < 8; ++j) {
            float c = tw[2 * j], s = tw[2 * j + 1];
            ar[j] = fmaf(g.x, c, fmaf(g.y, s, ar[j]));
            ai[j] = fmaf(g.y, c, fmaf(-g.x, s, ai[j]));
        }
    }
    float2* Pp = (float2*)P + (((size_t)hq * 136 + bn) * 32 + q_u * 8) * 64 + lane;
    #pragma unroll
    for (int j = 0; j < 8; ++j) Pp[j * 64] = make_float2(ar[j], ai[j]);
}

// K2b: reduce 4 hq-partials + mode mix. (unchanged from round 7)
__global__ __launch_bounds__(256) void k2b_mix(const float* __restrict__ P,
                                               const float* __restrict__ Wr,
                                               const float* __restrict__ Wi,
                                               float* __restrict__ Z) {
    __shared__ float2 xs[8 * 64];
    const int mn = blockIdx.x;
    const int m = mn & 31, n = mn >> 5;
    const int t = threadIdx.x;
    const int lane = t & 63;
    const int q = t >> 6;

    #pragma unroll
    for (int r = 0; r < 2; ++r) {
        int v = t + r * 256;
        int b = v >> 6, i = v & 63;
        const float2* Pp = (const float2*)P + (((size_t)(b * 17 + n)) * 32 + m) * 64 + i;
        float re = 0.f, im = 0.f;
        #pragma unroll
        for (int hq = 0; hq < HQ; ++hq) {
            float2 pv = Pp[(size_t)hq * (136 * 32 * 64)];
            re += pv.x; im += pv.y;
        }
        xs[v] = make_float2(re, im);
    }
    __syncthreads();

    const float scale = (n == 0 ? 1.0f : 2.0f) * (1.0f / 65536.0f);
    const int b0 = q * 2, b1 = b0 + 1;
    float z0r = 0, z0i = 0, z1r = 0, z1i = 0;
    const float* Wrp = Wr + (((size_t)m * 17 + n) * 64) * 64 + lane;
    const float* Wip = Wi + (((size_t)m * 17 + n) * 64) * 64 + lane;
    for (int i = 0; i < 64; ++i) {
        float wr = Wrp[(size_t)i * 64], wi = Wip[(size_t)i * 64];
        float2 x0 = xs[b0 * 64 + i], x1 = xs[b1 * 64 + i];
        z0r = fmaf(x0.x, wr, fmaf(-x0.y, wi, z0r));
        z0i = fmaf(x0.x, wi, fmaf(x0.y, wr, z0i));
        z1r = fmaf(x1.x, wr, fmaf(-x1.y, wi, z1r));
        z1i = fmaf(x1.x, wi, fmaf(x1.y, wr, z1i));
    }
    float2* Zp = (float2*)Z;
    Zp[(((size_t)b0 * 17 + n) * 32 + m) * 64 + lane] = make_float2(z0r * scale, z0i * scale);
    Zp[(((size_t)b1 * 17 + n) * 32 + m) * 64 + lane] = make_float2(z1r * scale, z1i * scale);
}

// K2c: inverse H-DFT. (unchanged from round 7)
__global__ __launch_bounds__(256) void k2c_ihdft(const float* __restrict__ Z,
                                                 const float* __restrict__ twB,
                                                 float* __restrict__ T) {
    __shared__ float2 zs[32 * 64];
    const int bn = blockIdx.x;
    const int b = bn / 17, n = bn % 17;
    const int hq = blockIdx.y;
    const int t = threadIdx.x;
    const int lane = t & 63;
    const int q_u = __builtin_amdgcn_readfirstlane(t >> 6);

    const float2* Zp = (const float2*)Z + (((size_t)b * 17 + n) * 32) * 64;
    #pragma unroll
    for (int r = 0; r < 8; ++r) zs[r * 256 + t] = Zp[r * 256 + t];
    __syncthreads();

    float2* Tb = (float2*)T + ((size_t)b * 256 * 17 + n) * 64 + lane;
    #pragma unroll 2
    for (int jj = 0; jj < 8; ++jj) {
        int h = hq * 32 + q_u * 8 + jj;
        const float* tw = twB + h * 64;
        float re0 = 0, im0 = 0, re1 = 0, im1 = 0;
        #pragma unroll
        for (int m = 0; m < 32; m += 2) {
            float2 z0 = zs[m * 64 + lane];
            float c0 = tw[2 * m + 0], s0 = tw[2 * m + 1];
            re0 = fmaf(z0.x, c0, fmaf(-z0.y, s0, re0));
            im0 = fmaf(z0.x, s0, fmaf(z0.y, c0, im0));
            float2 z1 = zs[(m + 1) * 64 + lane];
            float c1 = tw[2 * m + 2], s1 = tw[2 * m + 3];
            re1 = fmaf(z1.x, c1, fmaf(-z1.y, s1, re1));
            im1 = fmaf(z1.x, s1, fmaf(z1.y, c1, im1));
        }
        Tb[(size_t)h * (17 * 64)] = make_float2(re0 + re1, im0 + im1);
    }
}

// K3 (Horner): y[bh,w,o] = Re( sum_n T~[n,o] z^n ), z = cis(2pi w/256).
// z seeded EXACTLY at i^wq per wave, advanced by one literal-constant cmul per
// iteration. Inner loop: 68 FMA + 1 coalesced store, ZERO loads. 1 row/block,
// grid 2048, ~55 VGPR -> max occupancy. NREP reps over shifted rows.
__global__ __launch_bounds__(256) void k3_invW(const float* __restrict__ T,
                                               float* __restrict__ y) {
    const int tid = threadIdx.x;
    const int o = tid & 63;
    const int wq_u = __builtin_amdgcn_readfirstlane(tid >> 6);
    const float WR = 0.9996988186962042f;   // cos(2*pi/256)
    const float WS = 0.024541228522912288f; // sin(2*pi/256)

    #pragma unroll 1
    for (int rep = 0; rep < NREP; ++rep) {
        const int bh = (blockIdx.x + rep * 131) & 2047;  // bijection per rep

        const float2* T2 = (const float2*)T + (size_t)bh * 17 * 64;
        float tr[17], ti[17];
        #pragma unroll
        for (int n = 0; n < 17; ++n) {
            float2 v = T2[n * 64 + o];
            tr[n] = v.x; ti[n] = v.y;
        }

        // z = i^wq (exact)
        float zr = (wq_u == 0) ? 1.f : (wq_u == 2) ? -1.f : 0.f;
        float zi = (wq_u == 1) ? 1.f : (wq_u == 3) ? -1.f : 0.f;

        float* yb = y + (size_t)bh * (NW * NC) + (size_t)wq_u * 64 * 64 + o;
        #pragma unroll 2
        for (int ww = 0; ww < 64; ++ww) {
            // Horner: h = T[16]; h = h*z + T[n] for n=15..0; y = Re(h)
            float hr = tr[16], hi = ti[16];
            #pragma unroll
            for (int n = 15; n >= 0; --n) {
                float nr = fmaf(hr, zr, fmaf(-hi, zi, tr[n]));
                float ni = fmaf(hr, zi, fmaf(hi, zr, ti[n]));
                hr = nr; hi = ni;
            }
            yb[(size_t)ww * 64] = hr;   // coalesced 256B/wave
            // z *= cis(2pi/256)
            float t1 = zi * WS;
            float t2 = zi * WR;
            float nzr = fmaf(zr, WR, -t1);
            float nzi = fmaf(zr, WS, t2);
            zr = nzr; zi = nzi;
        }
    }
}

extern "C" void kernel_launch(void* const* d_in, const int* in_sizes, int n_in,
                              void* d_out, int out_size, void* d_ws, size_t ws_size,
                              hipStream_t stream) {
    (void)in_sizes; (void)n_in; (void)out_size; (void)ws_size;
    const float* x  = (const float*)d_in[0];
    const float* Wr = (const float*)d_in[1];
    const float* Wi = (const float*)d_in[2];
    float* out = (float*)d_out;
    float* ws  = (float*)d_ws;

    float* twA = ws;                 // 8704 floats
    float* twB = ws + 8704;          // 16384 floats
    float* G   = ws + 25088;         // 4456448 floats
    float* T   = G + 4456448;        // 4456448 floats
    float* P   = T;                  // alias: partials live in T's slot
    float* Z   = G;                  // alias: Z lives in dead G's slot

    k0_tw<<<32, 256, 0, stream>>>(twA, twB);
    k1_fwdW<<<NB * NH / 2, 256, 0, stream>>>(x, twA, G);
    k2a_hdft<<<dim3(NB * NM2, HQ), 256, 0, stream>>>(G, twB, P);
    k2b_mix<<<NM1 * NM2, 256, 0, stream>>>(P, Wr, Wi, Z);
    k2c_ihdft<<<dim3(NB * NM2, 8), 256, 0, stream>>>(Z, twB, T);
    k3_invW<<<NB * NH, 256, 0, stream>>>(T, out);
}

// Round 9
// 144.742 us; speedup vs baseline: 5.6040x; 5.6040x over previous
//
#include <hip/hip_runtime.h>

// FNO spectral convolution, truncated separable DFT formulation.
// B=8, H=W=256, C_IN=C_OUT=64, modes 32 x 17 (rows fftshift-centered: k_m = m-16).
//
// Round-9: k1 = real-coefficient Goertzel (2 VALU ops per (n,w,row), zero
// in-loop memory, SGPR-resident 2cos constants). k3 = direct eval from an
// LDS-staged padded twiddle table (2 FMA per (n,w,row), 9 wave-uniform
// ds_read_b128 broadcasts per w feeding 68 FMA for 2 rows).
// Round-8 NREP instrument showed: memory-free loops hit 72% VALUBusy; the
// only cost left was op-count inflation (4 ops vs the 2-op floor).
//
// ws layout (floats):
//   twA [256 w][18 pairs]  : 9216   (cos,sin of +2pi n w/256; pair 17 = zero pad)
//   twB [256 h][32 m][2]   : 16384
//   twC [32]               : 32     (2*cos(2pi n/256), n<17)
//   G   [B][H][17][64][2]  : 4456448   (aliased by Z after k2a)
//   T   [B][H][17][64][2]  : 4456448   (aliased by P before k2c)
//   P [4 hq][136 bn][32 m][64 i][2] -> lives in T's slot
//   Z [8 b][17 n][32 m][64 o][2]    -> lives in dead G's slot

#define NB 8
#define NH 256
#define NW 256
#define NC 64
#define NM1 32
#define NM2 17
#define HQ 4

__global__ void k0_tw(float* __restrict__ twA, float* __restrict__ twB,
                      float* __restrict__ twC) {
    const float STEP = 0.02454369260617026f; // 2*pi/256
    int t = blockIdx.x * 256 + threadIdx.x;
    if (t < 256 * 18) {
        int w = t / 18, nn = t % 18;
        if (nn < 17) {
            int ph = (nn * w) & 255;
            float ang = (float)ph * STEP;
            twA[w * 36 + 2 * nn + 0] = cosf(ang);
            twA[w * 36 + 2 * nn + 1] = sinf(ang);
        } else {
            twA[w * 36 + 34] = 0.f;
            twA[w * 36 + 35] = 0.f;
        }
    }
    if (t < 256 * 32) {
        int h = t >> 5, m = t & 31;
        int ph = ((m - 16) * h) & 255; // two's complement & 255 == mod 256
        float ang = (float)ph * STEP;
        twB[t * 2 + 0] = cosf(ang);
        twB[t * 2 + 1] = sinf(ang);
    }
    if (t < 17) {
        twC[t] = 2.0f * cosf((float)t * STEP);
    }
}

// K1 (real Goertzel): G[n][i] = sum_w x[bh,w,i] * cis(-2pi n w/256).
// Per wave-quarter: s_j = x_j + 2c_n s_{j-1} - s_{j-2} over its 64 w's
// (2 ops per n per row per sample, ZERO in-loop memory besides the 2 coalesced
// x loads), then fixup Q = (c s63 - s62) + i (sn s63), rotate by
// (-i)^{n(wq+1)}, 4-way LDS reduce. 2 rows/block, grid 1024.
__global__ __launch_bounds__(256) void k1_fwdW(const float* __restrict__ x,
                                               const float* __restrict__ twA,
                                               const float* __restrict__ twC,
                                               float* __restrict__ G) {
    __shared__ float lre[4][17][64];
    __shared__ float lim[4][17][64];
    const int tid = threadIdx.x;
    const int i = tid & 63;
    const int wq_u = __builtin_amdgcn_readfirstlane(tid >> 6);
    const int bh0 = blockIdx.x * 2;

    // wave-uniform constants -> s_load once
    float twoc[17], cn[17], sn[17];
    #pragma unroll
    for (int n = 0; n < 17; ++n) {
        twoc[n] = twC[n];
        cn[n] = twA[36 + 2 * n];      // row w=1: cis(2pi n/256)
        sn[n] = twA[36 + 2 * n + 1];
    }

    float s1a[17], s2a[17], s1b[17], s2b[17]; // rows 0,1
    #pragma unroll
    for (int n = 0; n < 17; ++n) { s1a[n]=0.f; s2a[n]=0.f; s1b[n]=0.f; s2b[n]=0.f; }

    const float* xb0 = x + (size_t)bh0 * (NW * NC) + (size_t)wq_u * 64 * 64 + i;
    const float* xb1 = xb0 + NW * NC;
    #pragma unroll 2
    for (int j = 0; j < 64; j += 2) {
        float x0a = xb0[(size_t)j * 64];        // coalesced 256B/wave
        float x0b = xb0[(size_t)(j + 1) * 64];
        float x1a = xb1[(size_t)j * 64];
        float x1b = xb1[(size_t)(j + 1) * 64];
        #pragma unroll
        for (int n = 0; n < 17; ++n) {
            float ta = fmaf(twoc[n], s1a[n], x0a) - s2a[n]; // s_j
            float tb = fmaf(twoc[n], ta, x0b) - s1a[n];     // s_{j+1}
            s2a[n] = ta; s1a[n] = tb;
            float ua = fmaf(twoc[n], s1b[n], x1a) - s2b[n];
            float ub = fmaf(twoc[n], ua, x1b) - s1b[n];
            s2b[n] = ua; s1b[n] = ub;
        }
    }

    // fixup + rotation; results into (s1*, s2*) = (re, im)
    #pragma unroll
    for (int n = 0; n < 17; ++n) {
        float qr0 = fmaf(cn[n], s1a[n], -s2a[n]);
        float qi0 = sn[n] * s1a[n];
        float qr1 = fmaf(cn[n], s1b[n], -s2b[n]);
        float qi1 = sn[n] * s1b[n];
        int k = (n * (wq_u + 1)) & 3;          // total rot = (-i)^{n(wq+1)}
        float r0r = (k==0)? qr0 : (k==1)? qi0 : (k==2)? -qr0 : -qi0;
        float r0i = (k==0)? qi0 : (k==1)? -qr0 : (k==2)? -qi0 : qr0;
        float r1r = (k==0)? qr1 : (k==1)? qi1 : (k==2)? -qr1 : -qi1;
        float r1i = (k==0)? qi1 : (k==1)? -qr1 : (k==2)? -qi1 : qr1;
        s1a[n] = r0r; s2a[n] = r0i;
        s1b[n] = r1r; s2b[n] = r1i;
    }

    // ---- reduce + store row 0 ----
    #pragma unroll
    for (int n = 0; n < 17; ++n) { lre[wq_u][n][i] = s1a[n]; lim[wq_u][n][i] = s2a[n]; }
    __syncthreads();
    float2* G0 = (float2*)G + (size_t)bh0 * 17 * 64;
    for (int n = wq_u; n < 17; n += 4) {
        float re = (lre[0][n][i] + lre[1][n][i]) + (lre[2][n][i] + lre[3][n][i]);
        float im = (lim[0][n][i] + lim[1][n][i]) + (lim[2][n][i] + lim[3][n][i]);
        G0[n * 64 + i] = make_float2(re, im);
    }
    __syncthreads();
    // ---- reduce + store row 1 ----
    #pragma unroll
    for (int n = 0; n < 17; ++n) { lre[wq_u][n][i] = s1b[n]; lim[wq_u][n][i] = s2b[n]; }
    __syncthreads();
    float2* G1 = G0 + 17 * 64;
    for (int n = wq_u; n < 17; n += 4) {
        float re = (lre[0][n][i] + lre[1][n][i]) + (lre[2][n][i] + lre[3][n][i]);
        float im = (lim[0][n][i] + lim[1][n][i]) + (lim[2][n][i] + lim[3][n][i]);
        G1[n * 64 + i] = make_float2(re, im);
    }
}

// K2a: partial H-DFT. grid (136 bn, 4 hq). (unchanged)
__global__ __launch_bounds__(256) void k2a_hdft(const float* __restrict__ G,
                                                const float* __restrict__ twB,
                                                float* __restrict__ P) {
    const int bn = blockIdx.x;
    const int b = bn / 17, n = bn % 17;
    const int hq = blockIdx.y;
    const int t = threadIdx.x;
    const int lane = t & 63;
    const int q_u = __builtin_amdgcn_readfirstlane(t >> 6);

    float ar[8], ai[8];
    #pragma unroll
    for (int j = 0; j < 8; ++j) { ar[j] = 0.f; ai[j] = 0.f; }

    const float2* Gb = (const float2*)G + ((size_t)b * 256 * 17 + n) * 64 + lane;
    #pragma unroll 2
    for (int hh = 0; hh < 64; ++hh) {
        int h = hq * 64 + hh;
        float2 g = Gb[(size_t)h * (17 * 64)];
        const float* tw = twB + (h * 32 + q_u * 8) * 2;
        #pragma unroll
        for (int j = 0; j < 8; ++j) {
            float c = tw[2 * j], s = tw[2 * j + 1];
            ar[j] = fmaf(g.x, c, fmaf(g.y, s, ar[j]));
            ai[j] = fmaf(g.y, c, fmaf(-g.x, s, ai[j]));
        }
    }
    float2* Pp = (float2*)P + (((size_t)hq * 136 + bn) * 32 + q_u * 8) * 64 + lane;
    #pragma unroll
    for (int j = 0; j < 8; ++j) Pp[j * 64] = make_float2(ar[j], ai[j]);
}

// K2b: reduce 4 hq-partials + mode mix. (unchanged)
__global__ __launch_bounds__(256) void k2b_mix(const float* __restrict__ P,
                                               const float* __restrict__ Wr,
                                               const float* __restrict__ Wi,
                                               float* __restrict__ Z) {
    __shared__ float2 xs[8 * 64];
    const int mn = blockIdx.x;
    const int m = mn & 31, n = mn >> 5;
    const int t = threadIdx.x;
    const int lane = t & 63;
    const int q = t >> 6;

    #pragma unroll
    for (int r = 0; r < 2; ++r) {
        int v = t + r * 256;
        int b = v >> 6, i = v & 63;
        const float2* Pp = (const float2*)P + (((size_t)(b * 17 + n)) * 32 + m) * 64 + i;
        float re = 0.f, im = 0.f;
        #pragma unroll
        for (int hq = 0; hq < HQ; ++hq) {
            float2 pv = Pp[(size_t)hq * (136 * 32 * 64)];
            re += pv.x; im += pv.y;
        }
        xs[v] = make_float2(re, im);
    }
    __syncthreads();

    const float scale = (n == 0 ? 1.0f : 2.0f) * (1.0f / 65536.0f);
    const int b0 = q * 2, b1 = b0 + 1;
    float z0r = 0, z0i = 0, z1r = 0, z1i = 0;
    const float* Wrp = Wr + (((size_t)m * 17 + n) * 64) * 64 + lane;
    const float* Wip = Wi + (((size_t)m * 17 + n) * 64) * 64 + lane;
    for (int i = 0; i < 64; ++i) {
        float wr = Wrp[(size_t)i * 64], wi = Wip[(size_t)i * 64];
        float2 x0 = xs[b0 * 64 + i], x1 = xs[b1 * 64 + i];
        z0r = fmaf(x0.x, wr, fmaf(-x0.y, wi, z0r));
        z0i = fmaf(x0.x, wi, fmaf(x0.y, wr, z0i));
        z1r = fmaf(x1.x, wr, fmaf(-x1.y, wi, z1r));
        z1i = fmaf(x1.x, wi, fmaf(x1.y, wr, z1i));
    }
    float2* Zp = (float2*)Z;
    Zp[(((size_t)b0 * 17 + n) * 32 + m) * 64 + lane] = make_float2(z0r * scale, z0i * scale);
    Zp[(((size_t)b1 * 17 + n) * 32 + m) * 64 + lane] = make_float2(z1r * scale, z1i * scale);
}

// K2c: inverse H-DFT. (unchanged)
__global__ __launch_bounds__(256) void k2c_ihdft(const float* __restrict__ Z,
                                                 const float* __restrict__ twB,
                                                 float* __restrict__ T) {
    __shared__ float2 zs[32 * 64];
    const int bn = blockIdx.x;
    const int b = bn / 17, n = bn % 17;
    const int hq = blockIdx.y;
    const int t = threadIdx.x;
    const int lane = t & 63;
    const int q_u = __builtin_amdgcn_readfirstlane(t >> 6);

    const float2* Zp = (const float2*)Z + (((size_t)b * 17 + n) * 32) * 64;
    #pragma unroll
    for (int r = 0; r < 8; ++r) zs[r * 256 + t] = Zp[r * 256 + t];
    __syncthreads();

    float2* Tb = (float2*)T + ((size_t)b * 256 * 17 + n) * 64 + lane;
    #pragma unroll 2
    for (int jj = 0; jj < 8; ++jj) {
        int h = hq * 32 + q_u * 8 + jj;
        const float* tw = twB + h * 64;
        float re0 = 0, im0 = 0, re1 = 0, im1 = 0;
        #pragma unroll
        for (int m = 0; m < 32; m += 2) {
            float2 z0 = zs[m * 64 + lane];
            float c0 = tw[2 * m + 0], s0 = tw[2 * m + 1];
            re0 = fmaf(z0.x, c0, fmaf(-z0.y, s0, re0));
            im0 = fmaf(z0.x, s0, fmaf(z0.y, c0, im0));
            float2 z1 = zs[(m + 1) * 64 + lane];
            float c1 = tw[2 * m + 2], s1 = tw[2 * m + 3];
            re1 = fmaf(z1.x, c1, fmaf(-z1.y, s1, re1));
            im1 = fmaf(z1.x, s1, fmaf(z1.y, c1, im1));
        }
        Tb[(size_t)h * (17 * 64)] = make_float2(re0 + re1, im0 + im1);
    }
}

// K3 (direct, LDS twiddle table): y[bh,w,o] = sum_n tr_n c[w,n] - ti_n s[w,n].
// Padded table [256 w][36] staged once per block (36.9 KB, 4 blocks/CU);
// per w: 9 wave-uniform ds_read_b128 broadcasts feed 68 FMA (2 rows) +
// 2 coalesced stores. 2 rows/block, grid 1024.
__global__ __launch_bounds__(256) void k3_invW(const float* __restrict__ T,
                                               const float* __restrict__ twA,
                                               float* __restrict__ y) {
    __shared__ float tws[256 * 36]; // 36.9 KB
    const int tid = threadIdx.x;
    const int o = tid & 63;
    const int wq_u = __builtin_amdgcn_readfirstlane(tid >> 6);
    const int bh0 = blockIdx.x * 2;

    // stage padded table: 2304 float4 = 9 per thread, coalesced
    {
        const float4* src = (const float4*)twA;
        float4* dst = (float4*)tws;
        #pragma unroll
        for (int r = 0; r < 9; ++r) dst[r * 256 + tid] = src[r * 256 + tid];
    }

    const float2* T0 = (const float2*)T + (size_t)bh0 * 17 * 64;
    const float2* T1 = T0 + 17 * 64;
    float tr0[17], ti0[17], tr1[17], ti1[17];
    #pragma unroll
    for (int n = 0; n < 17; ++n) {
        float2 v0 = T0[n * 64 + o];
        tr0[n] = v0.x; ti0[n] = v0.y;
        float2 v1 = T1[n * 64 + o];
        tr1[n] = v1.x; ti1[n] = v1.y;
    }
    __syncthreads();

    float* yb0 = y + (size_t)bh0 * (NW * NC);
    float* yb1 = yb0 + NW * NC;
    #pragma unroll 2
    for (int ww = 0; ww < 64; ++ww) {
        int w = wq_u * 64 + ww;
        const float* tw = &tws[w * 36];     // wave-uniform -> broadcast b128s
        float a0 = 0.f, a1 = 0.f, b0 = 0.f, b1 = 0.f;
        #pragma unroll
        for (int n = 0; n < 16; n += 2) {
            float c0 = tw[2 * n + 0], s0 = tw[2 * n + 1];
            float c1 = tw[2 * n + 2], s1v = tw[2 * n + 3];
            a0 = fmaf(tr0[n + 0], c0, fmaf(-ti0[n + 0], s0, a0));
            b0 = fmaf(tr1[n + 0], c0, fmaf(-ti1[n + 0], s0, b0));
            a1 = fmaf(tr0[n + 1], c1, fmaf(-ti0[n + 1], s1v, a1));
            b1 = fmaf(tr1[n + 1], c1, fmaf(-ti1[n + 1], s1v, b1));
        }
        float c16 = tw[32], s16 = tw[33];
        a0 = fmaf(tr0[16], c16, fmaf(-ti0[16], s16, a0));
        b0 = fmaf(tr1[16], c16, fmaf(-ti1[16], s16, b0));
        yb0[(size_t)w * 64 + o] = a0 + a1;  // coalesced 256B/wave
        yb1[(size_t)w * 64 + o] = b0 + b1;
    }
}

extern "C" void kernel_launch(void* const* d_in, const int* in_sizes, int n_in,
                              void* d_out, int out_size, void* d_ws, size_t ws_size,
                              hipStream_t stream) {
    (void)in_sizes; (void)n_in; (void)out_size; (void)ws_size;
    const float* x  = (const float*)d_in[0];
    const float* Wr = (const float*)d_in[1];
    const float* Wi = (const float*)d_in[2];
    float* out = (float*)d_out;
    float* ws  = (float*)d_ws;

    float* twA = ws;                 // 9216 floats (padded [256][36])
    float* twB = ws + 9216;          // 16384 floats
    float* twC = ws + 25600;         // 32 floats
    float* G   = ws + 25632;         // 4456448 floats
    float* T   = G + 4456448;        // 4456448 floats
    float* P   = T;                  // alias: partials live in T's slot
    float* Z   = G;                  // alias: Z lives in dead G's slot

    k0_tw<<<32, 256, 0, stream>>>(twA, twB, twC);
    k1_fwdW<<<NB * NH / 2, 256, 0, stream>>>(x, twA, twC, G);
    k2a_hdft<<<dim3(NB * NM2, HQ), 256, 0, stream>>>(G, twB, P);
    k2b_mix<<<NM1 * NM2, 256, 0, stream>>>(P, Wr, Wi, Z);
    k2c_ihdft<<<dim3(NB * NM2, 8), 256, 0, stream>>>(Z, twB, T);
    k3_invW<<<NB * NH / 2, 256, 0, stream>>>(T, twA, out);
}